// Round 1
// baseline (241.689 us; speedup 1.0000x reference)
//
#include <hip/hip_runtime.h>
#include <hip/hip_bf16.h>

// TT-Linear: out = (((x~(B,64,64) x C0) x C1) x C2) x C3 + bias
// Pipeline: transpose_cast(W1t,W2t) -> stage2 -> gemm1 -> gemm2 -> stage5

typedef _Float16 h8 __attribute__((ext_vector_type(8)));
typedef float f32x4 __attribute__((ext_vector_type(4)));

#define BATCH 8192

__device__ __forceinline__ void gld_lds16(const void* g, void* l) {
  __builtin_amdgcn_global_load_lds(
      (__attribute__((address_space(1))) void*)(g),
      (__attribute__((address_space(3))) void*)(l), 16, 0, 0);
}

// Build Wt[u][k] (fp16, U x K) from logical W[k][u] = src[srcrow(k)*U + u].
// PERM=1: srcrow(k) = (k&31)*64 + (k>>5)   (core1: k = d*32+r, src row r*64+d)
// PERM=0: srcrow(k) = k                     (core2 direct)
template <int PERM>
__global__ __launch_bounds__(256) void transpose_cast(
    const float* __restrict__ src, _Float16* __restrict__ dst, int K, int U) {
  __shared__ float t[64][65];
  const int k0 = blockIdx.x * 64, u0 = blockIdx.y * 64;
  const int tx = threadIdx.x & 63, ty = threadIdx.x >> 6;
  for (int i = ty; i < 64; i += 4) {
    const int k = k0 + i;
    const int sr = PERM ? ((k & 31) * 64 + (k >> 5)) : k;
    t[i][tx] = src[(size_t)sr * U + u0 + tx];
  }
  __syncthreads();
  for (int i = ty; i < 64; i += 4) {
    dst[(size_t)(u0 + i) * K + k0 + tx] = (_Float16)t[tx][i];
  }
}

// stage2: s1[b, d*32+r] = sum_c x[b, c*64+d] * C0[c*32+r], fp16 out
__global__ __launch_bounds__(256) void stage2(const float* __restrict__ x,
                                              const float* __restrict__ c0,
                                              _Float16* __restrict__ s1) {
  __shared__ float xl[4096];
  __shared__ float c0l[2048];
  const int b = blockIdx.x;
  {
    const int i = threadIdx.x;
    *(float4*)&xl[i * 4] = *(const float4*)&x[(size_t)b * 4096 + i * 4];
    *(float4*)&xl[1024 + i * 4] = *(const float4*)&x[(size_t)b * 4096 + 1024 + i * 4];
    *(float4*)&xl[2048 + i * 4] = *(const float4*)&x[(size_t)b * 4096 + 2048 + i * 4];
    *(float4*)&xl[3072 + i * 4] = *(const float4*)&x[(size_t)b * 4096 + 3072 + i * 4];
    if (i < 128) {
      *(float4*)&c0l[i * 4] = *(const float4*)&c0[i * 4];
      *(float4*)&c0l[512 + i * 4] = *(const float4*)&c0[512 + i * 4];
      *(float4*)&c0l[1024 + i * 4] = *(const float4*)&c0[1024 + i * 4];
      *(float4*)&c0l[1536 + i * 4] = *(const float4*)&c0[1536 + i * 4];
    }
  }
  __syncthreads();
  const int r = threadIdx.x & 31, dq = threadIdx.x >> 5;
  float acc[8];
#pragma unroll
  for (int it = 0; it < 8; ++it) acc[it] = 0.0f;
  for (int c = 0; c < 64; ++c) {
    const float wv = c0l[c * 32 + r];
#pragma unroll
    for (int it = 0; it < 8; ++it)
      acc[it] += xl[c * 64 + dq + 8 * it] * wv;
  }
#pragma unroll
  for (int it = 0; it < 8; ++it)
    s1[(size_t)b * 2048 + threadIdx.x + 256 * it] = (_Float16)acc[it];
}

// GEMM: C[m][n] = sum_k A[m][k] * Bt[n][k], fp16 in/out, fp32 MFMA accum.
// 128x128 tile, BK=64, 4 waves (2x2 of 64x64), m97 structure + T2 swizzle.
template <int M, int N, int K>
__global__ __launch_bounds__(256, 3) void gemm_tn(
    const _Float16* __restrict__ A, const _Float16* __restrict__ Bt,
    _Float16* __restrict__ C) {
  __shared__ _Float16 lA[128 * 64];
  __shared__ _Float16 lB[128 * 64];
  const int bm = blockIdx.x, bn = blockIdx.y;
  const int tid = threadIdx.x;
  const int w = tid >> 6, lane = tid & 63;
  const int wm = (w >> 1) << 6, wn = (w & 1) << 6;
  const int lr = lane & 15, kh = lane >> 4;

  f32x4 acc[4][4] = {};

  // Staging: wave w stages tile rows [w*32, w*32+32), 8 rows per inst.
  // LDS dest is linear; global SOURCE col is pre-swizzled (T2: both-sides).
  const int sr = (w << 5) + (lane >> 3);
  const int sc = ((lane & 7) ^ (lane >> 3)) << 4;  // swizzled byte col in [0,128)
  const char* gA = (const char*)(A + (size_t)(bm * 128 + sr) * K) + sc;
  const char* gB = (const char*)(Bt + (size_t)(bn * 128 + sr) * K) + sc;
  char* lAw = (char*)lA + w * 4096;
  char* lBw = (char*)lB + w * 4096;

  for (int kt = 0; kt < K / 64; ++kt) {
    __syncthreads();
    const size_t go = (size_t)kt * 128;
#pragma unroll
    for (int i = 0; i < 4; ++i) {
      gld_lds16(gA + go + (size_t)(i * 8) * (K * 2), lAw + i * 1024);
      gld_lds16(gB + go + (size_t)(i * 8) * (K * 2), lBw + i * 1024);
    }
    __syncthreads();
#pragma unroll
    for (int kk = 0; kk < 2; ++kk) {
      h8 af[4], bf[4];
#pragma unroll
      for (int m = 0; m < 4; ++m) {
        const int R = wm + m * 16 + lr;
        af[m] = *(const h8*)((const char*)lA + R * 128 +
                             ((((kk << 2) + kh) ^ (R & 7)) << 4));
      }
#pragma unroll
      for (int n = 0; n < 4; ++n) {
        const int R = wn + n * 16 + lr;
        bf[n] = *(const h8*)((const char*)lB + R * 128 +
                             ((((kk << 2) + kh) ^ (R & 7)) << 4));
      }
#pragma unroll
      for (int m = 0; m < 4; ++m)
#pragma unroll
        for (int n = 0; n < 4; ++n)
          acc[m][n] = __builtin_amdgcn_mfma_f32_16x16x32_f16(af[m], bf[n],
                                                             acc[m][n], 0, 0, 0);
    }
  }

#pragma unroll
  for (int m = 0; m < 4; ++m) {
    const int r0 = bm * 128 + wm + m * 16 + kh * 4;
#pragma unroll
    for (int n = 0; n < 4; ++n) {
      const int c0 = bn * 128 + wn + n * 16 + lr;
#pragma unroll
      for (int q = 0; q < 4; ++q)
        C[(size_t)(r0 + q) * N + c0] = (_Float16)acc[m][n][q];
    }
  }
}

// stage5: out[b, A*64+B2] = sum_t s3[b, A*32+t]*C3[t*64+B2] + bias
__global__ __launch_bounds__(256) void stage5(const _Float16* __restrict__ s3,
                                              const float* __restrict__ c3,
                                              const float* __restrict__ bias,
                                              float* __restrict__ out) {
  __shared__ _Float16 s3l[2048];
  __shared__ float c3l[2048];
  const int b = blockIdx.x;
  {
    const int i = threadIdx.x;
    *(h8*)&s3l[i * 8] = *(const h8*)&s3[(size_t)b * 2048 + i * 8];
    if (i < 128) {
      *(float4*)&c3l[i * 4] = *(const float4*)&c3[i * 4];
      *(float4*)&c3l[512 + i * 4] = *(const float4*)&c3[512 + i * 4];
      *(float4*)&c3l[1024 + i * 4] = *(const float4*)&c3[1024 + i * 4];
      *(float4*)&c3l[1536 + i * 4] = *(const float4*)&c3[1536 + i * 4];
    }
  }
  __syncthreads();
  const int B2 = threadIdx.x & 63, Aq = threadIdx.x >> 6;
#pragma unroll 4
  for (int it = 0; it < 16; ++it) {
    const int Ai = Aq + 4 * it;
    float acc = 0.0f;
#pragma unroll
    for (int tt = 0; tt < 32; ++tt)
      acc += (float)s3l[Ai * 32 + tt] * c3l[tt * 64 + B2];
    const int o = threadIdx.x + 256 * it;
    out[(size_t)b * 4096 + o] = acc + bias[o];
  }
}

extern "C" void kernel_launch(void* const* d_in, const int* in_sizes, int n_in,
                              void* d_out, int out_size, void* d_ws,
                              size_t ws_size, hipStream_t stream) {
  (void)in_sizes; (void)n_in; (void)out_size; (void)ws_size;
  const float* x     = (const float*)d_in[0];
  const float* core0 = (const float*)d_in[1];  // (1,64,32)
  const float* core1 = (const float*)d_in[2];  // (32,64,1024)
  const float* core2 = (const float*)d_in[3];  // (1024,64,32)
  const float* core3 = (const float*)d_in[4];  // (32,64,1)
  const float* bias  = (const float*)d_in[5];  // (4096,)
  float* out = (float*)d_out;

  char* ws = (char*)d_ws;
  _Float16* s1h = (_Float16*)ws;                        // 8192x2048 fp16 = 32MB (reused as s3)
  _Float16* s2h = (_Float16*)(ws + 33554432);           // 8192x1024 fp16 = 16MB
  _Float16* W1t = (_Float16*)(ws + 50331648);           // 1024x2048 fp16 = 4MB
  _Float16* W2t = (_Float16*)(ws + 54525952);           // 2048x1024 fp16 = 4MB

  transpose_cast<1><<<dim3(32, 16), 256, 0, stream>>>(core1, W1t, 2048, 1024);
  transpose_cast<0><<<dim3(16, 32), 256, 0, stream>>>(core2, W2t, 1024, 2048);
  stage2<<<BATCH, 256, 0, stream>>>(x, core0, s1h);
  gemm_tn<BATCH, 1024, 2048><<<dim3(BATCH / 128, 1024 / 128), 256, 0, stream>>>(s1h, W1t, s2h);
  gemm_tn<BATCH, 2048, 1024><<<dim3(BATCH / 128, 2048 / 128), 256, 0, stream>>>(s2h, W2t, s1h);
  stage5<<<BATCH, 256, 0, stream>>>(s1h, core3, bias, out);
}

// Round 2
// 175.675 us; speedup vs baseline: 1.3758x; 1.3758x over previous
//
#include <hip/hip_runtime.h>
#include <hip/hip_bf16.h>

// TT-Linear: out = (((x~(B,64,64) x C0) x C1) x C2) x C3 + bias
// Pipeline: transpose_cast(W1t,W2t) -> stage2 -> gemm1 -> gemm2 -> stage5

typedef _Float16 h4 __attribute__((ext_vector_type(4)));
typedef _Float16 h8 __attribute__((ext_vector_type(8)));
typedef float f32x4 __attribute__((ext_vector_type(4)));

#define BATCH 8192

__device__ __forceinline__ void gld_lds16(const void* g, void* l) {
  __builtin_amdgcn_global_load_lds(
      (__attribute__((address_space(1))) void*)(g),
      (__attribute__((address_space(3))) void*)(l), 16, 0, 0);
}

// Build Wt[u][k] (fp16, U x K) from logical W[k][u] = src[srcrow(k)*U + u].
// PERM=1: srcrow(k) = (k&31)*64 + (k>>5)   (core1: k = d*32+r, src row r*64+d)
// PERM=0: srcrow(k) = k                     (core2 direct)
template <int PERM>
__global__ __launch_bounds__(256) void transpose_cast(
    const float* __restrict__ src, _Float16* __restrict__ dst, int K, int U) {
  __shared__ float t[64][65];
  const int k0 = blockIdx.x * 64, u0 = blockIdx.y * 64;
  const int tx = threadIdx.x & 63, ty = threadIdx.x >> 6;
  for (int i = ty; i < 64; i += 4) {
    const int k = k0 + i;
    const int sr = PERM ? ((k & 31) * 64 + (k >> 5)) : k;
    t[i][tx] = src[(size_t)sr * U + u0 + tx];
  }
  __syncthreads();
  for (int i = ty; i < 64; i += 4) {
    dst[(size_t)(u0 + i) * K + k0 + tx] = (_Float16)t[tx][i];
  }
}

// stage2: s1[b, d*32+r] = sum_c x[b, c*64+d] * C0[c*32+r], fp16 out.
// 4 rows/block, x staged fp16 in LDS, thread computes 8d x 4r.
__global__ __launch_bounds__(256) void stage2(const float* __restrict__ x,
                                              const float* __restrict__ c0,
                                              _Float16* __restrict__ s1) {
  __shared__ _Float16 xh[4 * 4096];  // 32 KB
  __shared__ float c0l[2048];        // 8 KB
  const int b0 = blockIdx.x * 4;
  const int tid = threadIdx.x;

  {
    const float4* xg = (const float4*)(x + (size_t)b0 * 4096);
#pragma unroll
    for (int k = 0; k < 16; ++k) {
      float4 v = xg[tid + 256 * k];
      h4 w = {(_Float16)v.x, (_Float16)v.y, (_Float16)v.z, (_Float16)v.w};
      ((h4*)xh)[tid + 256 * k] = w;
    }
    ((float4*)c0l)[tid] = ((const float4*)c0)[tid];
    ((float4*)c0l)[tid + 256] = ((const float4*)c0)[tid + 256];
  }
  __syncthreads();

  const int row = tid >> 6, t6 = tid & 63;
  const int d0 = (t6 >> 3) * 8;  // high bits -> d (broadcast LDS read)
  const int r0 = (t6 & 7) * 4;   // low bits -> r (contiguous stores)
  const _Float16* xrow = xh + row * 4096;

  float acc[8][4];
#pragma unroll
  for (int i = 0; i < 8; ++i)
#pragma unroll
    for (int j = 0; j < 4; ++j) acc[i][j] = 0.0f;

  for (int c = 0; c < 64; ++c) {
    h8 xv = *(const h8*)&xrow[c * 64 + d0];
    f32x4 wv = *(const f32x4*)&c0l[c * 32 + r0];
#pragma unroll
    for (int i = 0; i < 8; ++i) {
      const float xf = (float)xv[i];
#pragma unroll
      for (int j = 0; j < 4; ++j) acc[i][j] += xf * wv[j];
    }
  }

  _Float16* s1row = s1 + (size_t)(b0 + row) * 2048;
#pragma unroll
  for (int i = 0; i < 8; ++i) {
    h4 o = {(_Float16)acc[i][0], (_Float16)acc[i][1], (_Float16)acc[i][2],
            (_Float16)acc[i][3]};
    *(h4*)&s1row[(d0 + i) * 32 + r0] = o;
  }
}

// GEMM: C[m][n] = sum_k A[m][k] * Bt[n][k], fp16 in/out, fp32 MFMA accum.
// 128x128 tile, BK=64, 4 waves (2x2 of 64x64), m97 structure + T2 swizzle.
template <int M, int N, int K>
__global__ __launch_bounds__(256, 3) void gemm_tn(
    const _Float16* __restrict__ A, const _Float16* __restrict__ Bt,
    _Float16* __restrict__ C) {
  __shared__ _Float16 lA[128 * 64];
  __shared__ _Float16 lB[128 * 64];
  const int bm = blockIdx.x, bn = blockIdx.y;
  const int tid = threadIdx.x;
  const int w = tid >> 6, lane = tid & 63;
  const int wm = (w >> 1) << 6, wn = (w & 1) << 6;
  const int lr = lane & 15, kh = lane >> 4;

  f32x4 acc[4][4] = {};

  const int sr = (w << 5) + (lane >> 3);
  const int sc = ((lane & 7) ^ (lane >> 3)) << 4;  // swizzled byte col
  const char* gA = (const char*)(A + (size_t)(bm * 128 + sr) * K) + sc;
  const char* gB = (const char*)(Bt + (size_t)(bn * 128 + sr) * K) + sc;
  char* lAw = (char*)lA + w * 4096;
  char* lBw = (char*)lB + w * 4096;

  for (int kt = 0; kt < K / 64; ++kt) {
    __syncthreads();
    const size_t go = (size_t)kt * 128;
#pragma unroll
    for (int i = 0; i < 4; ++i) {
      gld_lds16(gA + go + (size_t)(i * 8) * (K * 2), lAw + i * 1024);
      gld_lds16(gB + go + (size_t)(i * 8) * (K * 2), lBw + i * 1024);
    }
    __syncthreads();
#pragma unroll
    for (int kk = 0; kk < 2; ++kk) {
      h8 af[4], bf[4];
#pragma unroll
      for (int m = 0; m < 4; ++m) {
        const int R = wm + m * 16 + lr;
        af[m] = *(const h8*)((const char*)lA + R * 128 +
                             ((((kk << 2) + kh) ^ (R & 7)) << 4));
      }
#pragma unroll
      for (int n = 0; n < 4; ++n) {
        const int R = wn + n * 16 + lr;
        bf[n] = *(const h8*)((const char*)lB + R * 128 +
                             ((((kk << 2) + kh) ^ (R & 7)) << 4));
      }
#pragma unroll
      for (int m = 0; m < 4; ++m)
#pragma unroll
        for (int n = 0; n < 4; ++n)
          acc[m][n] = __builtin_amdgcn_mfma_f32_16x16x32_f16(af[m], bf[n],
                                                             acc[m][n], 0, 0, 0);
    }
  }

#pragma unroll
  for (int m = 0; m < 4; ++m) {
    const int r0 = bm * 128 + wm + m * 16 + kh * 4;
#pragma unroll
    for (int n = 0; n < 4; ++n) {
      const int c0 = bn * 128 + wn + n * 16 + lr;
#pragma unroll
      for (int q = 0; q < 4; ++q)
        C[(size_t)(r0 + q) * N + c0] = (_Float16)acc[m][n][q];
    }
  }
}

// stage5: out[b, A*64+B2] = sum_t s3[b, A*32+t]*C3[t*64+B2] + bias.
// 4 rows/block; s3 restaged transposed (s3t[t][A], f32); thread = 8A x 8B2.
__global__ __launch_bounds__(256) void stage5(const _Float16* __restrict__ s3,
                                              const float* __restrict__ c3,
                                              const float* __restrict__ bias,
                                              float* __restrict__ out) {
  __shared__ float s3t[4][2048];  // [row][t*64+A], 32 KB
  __shared__ float c3l[2048];     // [t*64+B2], 8 KB
  const int b0 = blockIdx.x * 4;
  const int tid = threadIdx.x;
  const int row = tid >> 6, t6 = tid & 63;

  {
    // stage s3 transposed: thread j of row loads h8 (8 t, fixed A)
    const _Float16* sg = s3 + (size_t)(b0 + row) * 2048;
    const int Aj = t6 & 15, t0 = (t6 >> 4) * 8;
#pragma unroll
    for (int k = 0; k < 4; ++k) {
      const int A = Aj + 16 * k;
      h8 v = *(const h8*)&sg[A * 32 + t0];
#pragma unroll
      for (int u = 0; u < 8; ++u) s3t[row][(t0 + u) * 64 + A] = (float)v[u];
    }
    ((float4*)c3l)[tid] = ((const float4*)c3)[tid];
    ((float4*)c3l)[tid + 256] = ((const float4*)c3)[tid + 256];
  }
  __syncthreads();

  const int A0 = (t6 >> 3) * 8;  // high bits -> A (broadcast reads)
  const int B0 = (t6 & 7) * 8;   // low bits -> B2 (contiguous stores)

  float acc[8][8];
#pragma unroll
  for (int i = 0; i < 8; ++i)
#pragma unroll
    for (int j = 0; j < 8; ++j) acc[i][j] = 0.0f;

  for (int t = 0; t < 32; ++t) {
    f32x4 sa0 = *(const f32x4*)&s3t[row][t * 64 + A0];
    f32x4 sa1 = *(const f32x4*)&s3t[row][t * 64 + A0 + 4];
    f32x4 cb0 = *(const f32x4*)&c3l[t * 64 + B0];
    f32x4 cb1 = *(const f32x4*)&c3l[t * 64 + B0 + 4];
#pragma unroll
    for (int i = 0; i < 4; ++i) {
#pragma unroll
      for (int j = 0; j < 4; ++j) {
        acc[i][j] += sa0[i] * cb0[j];
        acc[i][j + 4] += sa0[i] * cb1[j];
        acc[i + 4][j] += sa1[i] * cb0[j];
        acc[i + 4][j + 4] += sa1[i] * cb1[j];
      }
    }
  }

  float* orow = out + (size_t)(b0 + row) * 4096;
#pragma unroll
  for (int i = 0; i < 8; ++i) {
    const int o = (A0 + i) * 64 + B0;
    f32x4 bv0 = *(const f32x4*)&bias[o];
    f32x4 bv1 = *(const f32x4*)&bias[o + 4];
    f32x4 r0, r1;
#pragma unroll
    for (int j = 0; j < 4; ++j) {
      r0[j] = acc[i][j] + bv0[j];
      r1[j] = acc[i][j + 4] + bv1[j];
    }
    *(f32x4*)&orow[o] = r0;
    *(f32x4*)&orow[o + 4] = r1;
  }
}

extern "C" void kernel_launch(void* const* d_in, const int* in_sizes, int n_in,
                              void* d_out, int out_size, void* d_ws,
                              size_t ws_size, hipStream_t stream) {
  (void)in_sizes; (void)n_in; (void)out_size; (void)ws_size;
  const float* x     = (const float*)d_in[0];
  const float* core0 = (const float*)d_in[1];  // (1,64,32)
  const float* core1 = (const float*)d_in[2];  // (32,64,1024)
  const float* core2 = (const float*)d_in[3];  // (1024,64,32)
  const float* core3 = (const float*)d_in[4];  // (32,64,1)
  const float* bias  = (const float*)d_in[5];  // (4096,)
  float* out = (float*)d_out;

  char* ws = (char*)d_ws;
  _Float16* s1h = (_Float16*)ws;                        // 8192x2048 fp16 (reused as s3)
  _Float16* s2h = (_Float16*)(ws + 33554432);           // 8192x1024 fp16
  _Float16* W1t = (_Float16*)(ws + 50331648);           // 1024x2048 fp16
  _Float16* W2t = (_Float16*)(ws + 54525952);           // 2048x1024 fp16

  transpose_cast<1><<<dim3(32, 16), 256, 0, stream>>>(core1, W1t, 2048, 1024);
  transpose_cast<0><<<dim3(16, 32), 256, 0, stream>>>(core2, W2t, 1024, 2048);
  stage2<<<BATCH / 4, 256, 0, stream>>>(x, core0, s1h);
  gemm_tn<BATCH, 1024, 2048><<<dim3(BATCH / 128, 1024 / 128), 256, 0, stream>>>(s1h, W1t, s2h);
  gemm_tn<BATCH, 2048, 1024><<<dim3(BATCH / 128, 2048 / 128), 256, 0, stream>>>(s2h, W2t, s1h);
  stage5<<<BATCH / 4, 256, 0, stream>>>(s1h, core3, bias, out);
}

// Round 3
// 150.014 us; speedup vs baseline: 1.6111x; 1.1711x over previous
//
#include <hip/hip_runtime.h>
#include <hip/hip_bf16.h>

// TT-Linear: out = (((x~(B,64,64) x C0) x C1) x C2) x C3 + bias
// Pipeline: transpose_cast2 -> stage2 -> gemm1 -> gemm2_fused(+C3+bias)

typedef _Float16 h4 __attribute__((ext_vector_type(4)));
typedef _Float16 h8 __attribute__((ext_vector_type(8)));
typedef float f32x4 __attribute__((ext_vector_type(4)));

#define BATCH 8192

__device__ __forceinline__ void gld_lds16(const void* g, void* l) {
  __builtin_amdgcn_global_load_lds(
      (__attribute__((address_space(1))) void*)(g),
      (__attribute__((address_space(3))) void*)(l), 16, 0, 0);
}

// Both weight transposes in one launch. grid (32,16,2).
// z=0: W1t[u][k], K=2048,U=1024, srcrow(k)=(k&31)*64+(k>>5)  (core1)
// z=1: W2t[u][k], K=1024,U=2048, srcrow(k)=k                  (core2)
__global__ __launch_bounds__(256) void transpose_cast2(
    const float* __restrict__ c1, _Float16* __restrict__ W1t,
    const float* __restrict__ c2, _Float16* __restrict__ W2t) {
  __shared__ float t[64][65];
  const int which = blockIdx.z;
  const float* src = which ? c2 : c1;
  _Float16* dst = which ? W2t : W1t;
  const int K = which ? 1024 : 2048, U = which ? 2048 : 1024;
  const int k0 = (which ? blockIdx.y : blockIdx.x) * 64;
  const int u0 = (which ? blockIdx.x : blockIdx.y) * 64;
  const int tx = threadIdx.x & 63, ty = threadIdx.x >> 6;
  for (int i = ty; i < 64; i += 4) {
    const int k = k0 + i;
    const int sr = which ? k : ((k & 31) * 64 + (k >> 5));
    t[i][tx] = src[(size_t)sr * U + u0 + tx];
  }
  __syncthreads();
  for (int i = ty; i < 64; i += 4) {
    dst[(size_t)(u0 + i) * K + k0 + tx] = (_Float16)t[tx][i];
  }
}

// stage2: s1[b, d*32+r] = sum_c x[b, c*64+d] * C0[c*32+r], fp16 out.
// 4 rows/block, x staged fp16 in LDS, thread computes 8d x 4r.
__global__ __launch_bounds__(256) void stage2(const float* __restrict__ x,
                                              const float* __restrict__ c0,
                                              _Float16* __restrict__ s1) {
  __shared__ _Float16 xh[4 * 4096];  // 32 KB
  __shared__ float c0l[2048];        // 8 KB
  const int b0 = blockIdx.x * 4;
  const int tid = threadIdx.x;

  {
    const float4* xg = (const float4*)(x + (size_t)b0 * 4096);
#pragma unroll
    for (int k = 0; k < 16; ++k) {
      float4 v = xg[tid + 256 * k];
      h4 w = {(_Float16)v.x, (_Float16)v.y, (_Float16)v.z, (_Float16)v.w};
      ((h4*)xh)[tid + 256 * k] = w;
    }
    ((float4*)c0l)[tid] = ((const float4*)c0)[tid];
    ((float4*)c0l)[tid + 256] = ((const float4*)c0)[tid + 256];
  }
  __syncthreads();

  const int row = tid >> 6, t6 = tid & 63;
  const int d0 = (t6 >> 3) * 8;  // high bits -> d (broadcast LDS read)
  const int r0 = (t6 & 7) * 4;   // low bits -> r (contiguous stores)
  const _Float16* xrow = xh + row * 4096;

  float acc[8][4];
#pragma unroll
  for (int i = 0; i < 8; ++i)
#pragma unroll
    for (int j = 0; j < 4; ++j) acc[i][j] = 0.0f;

  for (int c = 0; c < 64; ++c) {
    h8 xv = *(const h8*)&xrow[c * 64 + d0];
    f32x4 wv = *(const f32x4*)&c0l[c * 32 + r0];
#pragma unroll
    for (int i = 0; i < 8; ++i) {
      const float xf = (float)xv[i];
#pragma unroll
      for (int j = 0; j < 4; ++j) acc[i][j] += xf * wv[j];
    }
  }

  _Float16* s1row = s1 + (size_t)(b0 + row) * 2048;
#pragma unroll
  for (int i = 0; i < 8; ++i) {
    h4 o = {(_Float16)acc[i][0], (_Float16)acc[i][1], (_Float16)acc[i][2],
            (_Float16)acc[i][3]};
    *(h4*)&s1row[(d0 + i) * 32 + r0] = o;
  }
}

// GEMM: C[m][n] = sum_k A[m][k] * Bt[n][k], fp16 in/out, fp32 MFMA accum.
// 128x128 tile, BK=64, 4 waves (2x2 of 64x64), m97 structure + T2 swizzle.
template <int M, int N, int K>
__global__ __launch_bounds__(256, 3) void gemm_tn(
    const _Float16* __restrict__ A, const _Float16* __restrict__ Bt,
    _Float16* __restrict__ C) {
  __shared__ _Float16 lA[128 * 64];
  __shared__ _Float16 lB[128 * 64];
  const int bm = blockIdx.x, bn = blockIdx.y;
  const int tid = threadIdx.x;
  const int w = tid >> 6, lane = tid & 63;
  const int wm = (w >> 1) << 6, wn = (w & 1) << 6;
  const int lr = lane & 15, kh = lane >> 4;

  f32x4 acc[4][4] = {};

  const int sr = (w << 5) + (lane >> 3);
  const int sc = ((lane & 7) ^ (lane >> 3)) << 4;  // swizzled byte col
  const char* gA = (const char*)(A + (size_t)(bm * 128 + sr) * K) + sc;
  const char* gB = (const char*)(Bt + (size_t)(bn * 128 + sr) * K) + sc;
  char* lAw = (char*)lA + w * 4096;
  char* lBw = (char*)lB + w * 4096;

  for (int kt = 0; kt < K / 64; ++kt) {
    __syncthreads();
    const size_t go = (size_t)kt * 128;
#pragma unroll
    for (int i = 0; i < 4; ++i) {
      gld_lds16(gA + go + (size_t)(i * 8) * (K * 2), lAw + i * 1024);
      gld_lds16(gB + go + (size_t)(i * 8) * (K * 2), lBw + i * 1024);
    }
    __syncthreads();
#pragma unroll
    for (int kk = 0; kk < 2; ++kk) {
      h8 af[4], bf[4];
#pragma unroll
      for (int m = 0; m < 4; ++m) {
        const int R = wm + m * 16 + lr;
        af[m] = *(const h8*)((const char*)lA + R * 128 +
                             ((((kk << 2) + kh) ^ (R & 7)) << 4));
      }
#pragma unroll
      for (int n = 0; n < 4; ++n) {
        const int R = wn + n * 16 + lr;
        bf[n] = *(const h8*)((const char*)lB + R * 128 +
                             ((((kk << 2) + kh) ^ (R & 7)) << 4));
      }
#pragma unroll
      for (int m = 0; m < 4; ++m)
#pragma unroll
        for (int n = 0; n < 4; ++n)
          acc[m][n] = __builtin_amdgcn_mfma_f32_16x16x32_f16(af[m], bf[n],
                                                             acc[m][n], 0, 0, 0);
    }
  }

#pragma unroll
  for (int m = 0; m < 4; ++m) {
    const int r0 = bm * 128 + wm + m * 16 + kh * 4;
#pragma unroll
    for (int n = 0; n < 4; ++n) {
      const int c0 = bn * 128 + wn + n * 16 + lr;
#pragma unroll
      for (int q = 0; q < 4; ++q)
        C[(size_t)(r0 + q) * N + c0] = (_Float16)acc[m][n][q];
    }
  }
}

// gemm2 fused with stage5: s3-tile (128x128 = 4 A-values x 32 t) stays in
// LDS; epilogue does out[b, A*64+B2] = sum_t s3*C3 + bias via one MFMA
// k-step (K=32 = t). Writes f32 out directly; s3 never hits global.
template <int M, int K>
__global__ __launch_bounds__(256, 3) void gemm2_fused(
    const _Float16* __restrict__ A, const _Float16* __restrict__ Bt,
    const float* __restrict__ c3, const float* __restrict__ bias,
    float* __restrict__ out) {
  __shared__ _Float16 lds[128 * 128];  // main: lA | lB ; epilogue: S[128][128]
  _Float16* lA = lds;
  _Float16* lB = lds + 128 * 64;
  const int bm = blockIdx.x, bn = blockIdx.y;
  const int tid = threadIdx.x;
  const int w = tid >> 6, lane = tid & 63;
  const int wm = (w >> 1) << 6, wn = (w & 1) << 6;
  const int lr = lane & 15, kh = lane >> 4;

  f32x4 acc[4][4] = {};

  const int sr = (w << 5) + (lane >> 3);
  const int sc = ((lane & 7) ^ (lane >> 3)) << 4;
  const char* gA = (const char*)(A + (size_t)(bm * 128 + sr) * K) + sc;
  const char* gB = (const char*)(Bt + (size_t)(bn * 128 + sr) * K) + sc;
  char* lAw = (char*)lA + w * 4096;
  char* lBw = (char*)lB + w * 4096;

  for (int kt = 0; kt < K / 64; ++kt) {
    __syncthreads();
    const size_t go = (size_t)kt * 128;
#pragma unroll
    for (int i = 0; i < 4; ++i) {
      gld_lds16(gA + go + (size_t)(i * 8) * (K * 2), lAw + i * 1024);
      gld_lds16(gB + go + (size_t)(i * 8) * (K * 2), lBw + i * 1024);
    }
    __syncthreads();
#pragma unroll
    for (int kk = 0; kk < 2; ++kk) {
      h8 af[4], bf[4];
#pragma unroll
      for (int m = 0; m < 4; ++m) {
        const int R = wm + m * 16 + lr;
        af[m] = *(const h8*)((const char*)lA + R * 128 +
                             ((((kk << 2) + kh) ^ (R & 7)) << 4));
      }
#pragma unroll
      for (int n = 0; n < 4; ++n) {
        const int R = wn + n * 16 + lr;
        bf[n] = *(const h8*)((const char*)lB + R * 128 +
                             ((((kk << 2) + kh) ^ (R & 7)) << 4));
      }
#pragma unroll
      for (int m = 0; m < 4; ++m)
#pragma unroll
        for (int n = 0; n < 4; ++n)
          acc[m][n] = __builtin_amdgcn_mfma_f32_16x16x32_f16(af[m], bf[n],
                                                             acc[m][n], 0, 0, 0);
    }
  }

  // ---- epilogue: out-tile = S(128x[4A x 32t]) x C3(32x64) + bias ----
  __syncthreads();  // everyone done reading lA/lB

  // B-fragments (C3) and bias, per-lane, from global (L2/L3 resident)
  h8 bfe[4];
  float bb[4][4];
#pragma unroll
  for (int n = 0; n < 4; ++n) {
#pragma unroll
    for (int j = 0; j < 8; ++j)
      bfe[n][j] = (_Float16)c3[(kh * 8 + j) * 64 + n * 16 + lr];
#pragma unroll
    for (int a = 0; a < 4; ++a)
      bb[a][n] = bias[bn * 256 + a * 64 + n * 16 + lr];
  }

  // write acc tile to S[128][128] fp16, chunk^(row&7) swizzle (256B rows)
#pragma unroll
  for (int m = 0; m < 4; ++m) {
    const int Rb = wm + m * 16 + kh * 4;
#pragma unroll
    for (int n = 0; n < 4; ++n) {
      const int cc = wn + n * 16 + lr;
#pragma unroll
      for (int q = 0; q < 4; ++q) {
        const int R = Rb + q;
        const int byte =
            R * 256 + ((((cc >> 3) ^ (R & 7)) << 4) | ((cc & 7) << 1));
        *(_Float16*)((char*)lds + byte) = (_Float16)acc[m][n][q];
      }
    }
  }
  __syncthreads();

  // wave w owns output rows [w*32, w*32+32)
  const int wrow = w << 5;
#pragma unroll
  for (int mi = 0; mi < 2; ++mi) {
    const int row = wrow + mi * 16 + lr;  // A-frag row
    const int orow0 = bm * 128 + wrow + mi * 16 + kh * 4;
#pragma unroll
    for (int a = 0; a < 4; ++a) {
      h8 af = *(const h8*)((const char*)lds + row * 256 +
                           ((((a << 2) + kh) ^ (row & 7)) << 4));
#pragma unroll
      for (int n = 0; n < 4; ++n) {
        f32x4 d = {};
        d = __builtin_amdgcn_mfma_f32_16x16x32_f16(af, bfe[n], d, 0, 0, 0);
        const int ocol = bn * 256 + a * 64 + n * 16 + lr;
#pragma unroll
        for (int q = 0; q < 4; ++q)
          out[(size_t)(orow0 + q) * 4096 + ocol] = d[q] + bb[a][n];
      }
    }
  }
}

extern "C" void kernel_launch(void* const* d_in, const int* in_sizes, int n_in,
                              void* d_out, int out_size, void* d_ws,
                              size_t ws_size, hipStream_t stream) {
  (void)in_sizes; (void)n_in; (void)out_size; (void)ws_size;
  const float* x     = (const float*)d_in[0];
  const float* core0 = (const float*)d_in[1];  // (1,64,32)
  const float* core1 = (const float*)d_in[2];  // (32,64,1024)
  const float* core2 = (const float*)d_in[3];  // (1024,64,32)
  const float* core3 = (const float*)d_in[4];  // (32,64,1)
  const float* bias  = (const float*)d_in[5];  // (4096,)
  float* out = (float*)d_out;

  char* ws = (char*)d_ws;
  _Float16* s1h = (_Float16*)ws;                        // 8192x2048 fp16
  _Float16* s2h = (_Float16*)(ws + 33554432);           // 8192x1024 fp16
  _Float16* W1t = (_Float16*)(ws + 50331648);           // 1024x2048 fp16
  _Float16* W2t = (_Float16*)(ws + 54525952);           // 2048x1024 fp16

  transpose_cast2<<<dim3(32, 16, 2), 256, 0, stream>>>(core1, W1t, core2, W2t);
  stage2<<<BATCH / 4, 256, 0, stream>>>(x, core0, s1h);
  gemm_tn<BATCH, 1024, 2048><<<dim3(BATCH / 128, 1024 / 128), 256, 0, stream>>>(s1h, W1t, s2h);
  gemm2_fused<BATCH, 1024><<<dim3(BATCH / 128, 2048 / 128), 256, 0, stream>>>(s2h, W2t, core3, bias, out);
}